// Round 1
// baseline (97.523 us; speedup 1.0000x reference)
//
#include <hip/hip_runtime.h>
#include <math.h>

#define IMG_S 256
#define NFACE 500
#define TSZ 6
#define DIST 2.732f

// LDS layout per face: 3 x float4:
//  q0 = (A0, B0, C0, A1)
//  q1 = (B1, C1, A2, B2)
//  q2 = (C2, Az, Bz, Cz)
// w_i = A_i*px + B_i*py + C_i  (edge fn pre-multiplied by 1/area)
// z   = Az*px + Bz*py + Cz

__device__ __forceinline__ void edge_coef(float ax, float ay, float bx, float by,
                                          float inv, float& A, float& B, float& C) {
    float dy = by - ay;
    float dx = bx - ax;
    A = dy * inv;
    B = -dx * inv;
    C = (ay * dx - ax * dy) * inv;
}

__global__ __launch_bounds__(256) void render_loss_kernel(
    const float* __restrict__ verts,   // 252*3
    const int*   __restrict__ faces,   // 500*3
    const float* __restrict__ tex,     // 500*6*6*6*3
    const float* __restrict__ ref0,    // 3*256*256 (view 0: eye=+D)
    const float* __restrict__ ref1,    // 3*256*256 (view 1: eye=-D)
    float*       __restrict__ partials)
{
    __shared__ float4 fc[NFACE][3];
    __shared__ float red[4];

    const int view = blockIdx.y;

    // ---- per-block face setup (redundant across blocks; trivial cost) ----
    for (int f = threadIdx.x; f < NFACE; f += blockDim.x) {
        int i0 = faces[f * 3 + 0];
        int i1 = faces[f * 3 + 1];
        int i2 = faces[f * 3 + 2];

        float v0x = verts[i0 * 3 + 0], v0y = verts[i0 * 3 + 1], v0z = verts[i0 * 3 + 2];
        float v1x = verts[i1 * 3 + 0], v1y = verts[i1 * 3 + 1], v1z = verts[i1 * 3 + 2];
        float v2x = verts[i2 * 3 + 0], v2y = verts[i2 * 3 + 1], v2z = verts[i2 * 3 + 2];

        float p0x, p0y, p0z, p1x, p1y, p1z, p2x, p2y, p2z;
        if (view == 0) {
            // eye=(0,0,+D): R rows x=(-1,0,0) y=(0,1,0) z=(0,0,-1); v'=(-x, y, D-z)
            p0x = -v0x; p0y = v0y; p0z = DIST - v0z;
            p1x = -v1x; p1y = v1y; p1z = DIST - v1z;
            p2x = -v2x; p2y = v2y; p2z = DIST - v2z;
        } else {
            // eye=(0,0,-D): v'=(x, y, z+D)
            p0x = v0x; p0y = v0y; p0z = v0z + DIST;
            p1x = v1x; p1y = v1y; p1z = v1z + DIST;
            p2x = v2x; p2y = v2y; p2z = v2z + DIST;
        }

        float area = (p1x - p0x) * (p2y - p0y) - (p1y - p0y) * (p2x - p0x);
        bool ok = fabsf(area) > 1e-8f;

        float A0, B0, C0, A1, B1, C1, A2, B2, C2, Az, Bz, Cz;
        if (ok) {
            float inv = 1.0f / area;
            edge_coef(p1x, p1y, p2x, p2y, inv, A0, B0, C0);  // e0 = edge(p1,p2)
            edge_coef(p2x, p2y, p0x, p0y, inv, A1, B1, C1);  // e1 = edge(p2,p0)
            edge_coef(p0x, p0y, p1x, p1y, inv, A2, B2, C2);  // e2 = edge(p0,p1)
            Az = A0 * p0z + A1 * p1z + A2 * p2z;
            Bz = B0 * p0z + B1 * p1z + B2 * p2z;
            Cz = C0 * p0z + C1 * p1z + C2 * p2z;
        } else {
            // force w = -1 so inside-test always fails (matches ref's ok-mask)
            A0 = B0 = A1 = B1 = A2 = B2 = 0.0f;
            C0 = C1 = C2 = -1.0f;
            Az = Bz = 0.0f; Cz = 0.0f;
        }
        fc[f][0] = make_float4(A0, B0, C0, A1);
        fc[f][1] = make_float4(B1, C1, A2, B2);
        fc[f][2] = make_float4(C2, Az, Bz, Cz);
    }
    __syncthreads();

    // ---- per-pixel raster loop ----
    const int pix = blockIdx.x * blockDim.x + threadIdx.x;   // 0..65535
    const int ix = pix & (IMG_S - 1);
    const int iy = pix >> 8;
    const float px = (2.0f * (float)ix + 1.0f - (float)IMG_S) * (1.0f / (float)IMG_S);
    const float py = -((2.0f * (float)iy + 1.0f - (float)IMG_S) * (1.0f / (float)IMG_S));

    float bestz = INFINITY;
    int besti = -1;

    for (int f = 0; f < NFACE; ++f) {
        float4 q0 = fc[f][0];
        float4 q1 = fc[f][1];
        float4 q2 = fc[f][2];
        float w0 = fmaf(px, q0.x, fmaf(py, q0.y, q0.z));
        float w1 = fmaf(px, q0.w, fmaf(py, q1.x, q1.y));
        float w2 = fmaf(px, q1.z, fmaf(py, q1.w, q2.x));
        float z  = fmaf(px, q2.y, fmaf(py, q2.z, q2.w));
        float wmin = fminf(w0, fminf(w1, w2));
        bool c = (wmin >= 0.0f) && (z > 0.0f) && (z < bestz);
        bestz = c ? z : bestz;   // strict < keeps first index on ties (argmin semantics)
        besti = c ? f : besti;
    }

    float c0 = 0.0f, c1 = 0.0f, c2 = 0.0f;
    if (besti >= 0) {
        float4 q0 = fc[besti][0];
        float4 q1 = fc[besti][1];
        float4 q2 = fc[besti][2];
        float w0 = fmaf(px, q0.x, fmaf(py, q0.y, q0.z));
        float w1 = fmaf(px, q0.w, fmaf(py, q1.x, q1.y));
        float w2 = fmaf(px, q1.z, fmaf(py, q1.w, q2.x));
        // ti = clip(round_half_even(w*5), 0, 5)
        int t0 = (int)fminf(fmaxf(rintf(w0 * (float)(TSZ - 1)), 0.0f), (float)(TSZ - 1));
        int t1 = (int)fminf(fmaxf(rintf(w1 * (float)(TSZ - 1)), 0.0f), (float)(TSZ - 1));
        int t2 = (int)fminf(fmaxf(rintf(w2 * (float)(TSZ - 1)), 0.0f), (float)(TSZ - 1));
        int flat = ((besti * TSZ + t0) * TSZ + t1) * TSZ + t2;
        const float* t = tex + (long)flat * 3;
        c0 = tanhf(t[0]);
        c1 = tanhf(t[1]);
        c2 = tanhf(t[2]);
    }

    const float* __restrict__ ref = (view == 0) ? ref0 : ref1;
    float d0 = c0 - ref[0 * IMG_S * IMG_S + pix];
    float d1 = c1 - ref[1 * IMG_S * IMG_S + pix];
    float d2 = c2 - ref[2 * IMG_S * IMG_S + pix];
    float acc = fmaf(d0, d0, fmaf(d1, d1, d2 * d2));

    // ---- block reduction ----
    for (int off = 32; off > 0; off >>= 1)
        acc += __shfl_down(acc, off, 64);
    int lane = threadIdx.x & 63;
    int wid = threadIdx.x >> 6;
    if (lane == 0) red[wid] = acc;
    __syncthreads();
    if (threadIdx.x == 0) {
        partials[blockIdx.y * gridDim.x + blockIdx.x] = red[0] + red[1] + red[2] + red[3];
    }
}

__global__ __launch_bounds__(256) void reduce_kernel(const float* __restrict__ partials,
                                                     int n, float* __restrict__ out) {
    __shared__ float red[4];
    float v = 0.0f;
    for (int i = threadIdx.x; i < n; i += 256) v += partials[i];
    for (int off = 32; off > 0; off >>= 1)
        v += __shfl_down(v, off, 64);
    int lane = threadIdx.x & 63;
    int wid = threadIdx.x >> 6;
    if (lane == 0) red[wid] = v;
    __syncthreads();
    if (threadIdx.x == 0) {
        out[0] = 0.5f * (red[0] + red[1] + red[2] + red[3]);
    }
}

extern "C" void kernel_launch(void* const* d_in, const int* in_sizes, int n_in,
                              void* d_out, int out_size, void* d_ws, size_t ws_size,
                              hipStream_t stream) {
    const float* verts = (const float*)d_in[0];
    const int*   faces = (const int*)d_in[1];
    const float* tex   = (const float*)d_in[2];
    const float* ref0  = (const float*)d_in[3];
    const float* ref1  = (const float*)d_in[4];
    float* out = (float*)d_out;
    float* partials = (float*)d_ws;

    const int blocks_per_view = (IMG_S * IMG_S) / 256;  // 256
    dim3 grid(blocks_per_view, 2);
    render_loss_kernel<<<grid, 256, 0, stream>>>(verts, faces, tex, ref0, ref1, partials);
    reduce_kernel<<<1, 256, 0, stream>>>(partials, blocks_per_view * 2, out);
}

// Round 2
// 93.783 us; speedup vs baseline: 1.0399x; 1.0399x over previous
//
#include <hip/hip_runtime.h>
#include <math.h>

#define IMG_S 256
#define NPIX (IMG_S * IMG_S)
#define NFACE 500
#define NCHUNK 4
#define FPC (NFACE / NCHUNK)   // 125
#define TSZ 6
#define DIST 2.732f

// w_i = A_i*px + B_i*py + C_i  (edge fn pre-multiplied by 1/area)
// z   = Az*px + Bz*py + Cz
struct FaceCoef {
    float A0, B0, C0, A1, B1, C1, A2, B2, C2, Az, Bz, Cz;
};

__device__ __forceinline__ void edge_coef(float ax, float ay, float bx, float by,
                                          float inv, float& A, float& B, float& C) {
    float dy = by - ay;
    float dx = bx - ax;
    A = dy * inv;
    B = -dx * inv;
    C = (ay * dx - ax * dy) * inv;
}

// IDENTICAL helper used by both passes -> bit-exact w agreement.
__device__ __forceinline__ FaceCoef compute_face(const float* __restrict__ verts,
                                                 const int* __restrict__ faces,
                                                 int f, int view) {
    int i0 = faces[f * 3 + 0];
    int i1 = faces[f * 3 + 1];
    int i2 = faces[f * 3 + 2];

    float v0x = verts[i0 * 3 + 0], v0y = verts[i0 * 3 + 1], v0z = verts[i0 * 3 + 2];
    float v1x = verts[i1 * 3 + 0], v1y = verts[i1 * 3 + 1], v1z = verts[i1 * 3 + 2];
    float v2x = verts[i2 * 3 + 0], v2y = verts[i2 * 3 + 1], v2z = verts[i2 * 3 + 2];

    float p0x, p0y, p0z, p1x, p1y, p1z, p2x, p2y, p2z;
    if (view == 0) {
        // eye=(0,0,+D): v'=(-x, y, D-z)
        p0x = -v0x; p0y = v0y; p0z = DIST - v0z;
        p1x = -v1x; p1y = v1y; p1z = DIST - v1z;
        p2x = -v2x; p2y = v2y; p2z = DIST - v2z;
    } else {
        // eye=(0,0,-D): v'=(x, y, z+D)
        p0x = v0x; p0y = v0y; p0z = v0z + DIST;
        p1x = v1x; p1y = v1y; p1z = v1z + DIST;
        p2x = v2x; p2y = v2y; p2z = v2z + DIST;
    }

    float area = (p1x - p0x) * (p2y - p0y) - (p1y - p0y) * (p2x - p0x);
    bool ok = fabsf(area) > 1e-8f;

    FaceCoef fc;
    if (ok) {
        float inv = 1.0f / area;
        edge_coef(p1x, p1y, p2x, p2y, inv, fc.A0, fc.B0, fc.C0);  // e0 = edge(p1,p2)
        edge_coef(p2x, p2y, p0x, p0y, inv, fc.A1, fc.B1, fc.C1);  // e1 = edge(p2,p0)
        edge_coef(p0x, p0y, p1x, p1y, inv, fc.A2, fc.B2, fc.C2);  // e2 = edge(p0,p1)
        fc.Az = fc.A0 * p0z + fc.A1 * p1z + fc.A2 * p2z;
        fc.Bz = fc.B0 * p0z + fc.B1 * p1z + fc.B2 * p2z;
        fc.Cz = fc.C0 * p0z + fc.C1 * p1z + fc.C2 * p2z;
    } else {
        fc.A0 = fc.B0 = fc.A1 = fc.B1 = fc.A2 = fc.B2 = 0.0f;
        fc.C0 = fc.C1 = fc.C2 = -1.0f;   // inside-test always fails
        fc.Az = fc.Bz = fc.Cz = 0.0f;
    }
    return fc;
}

__device__ __forceinline__ float pix_x(int ix) {
    return (2.0f * (float)ix + 1.0f - (float)IMG_S) * (1.0f / (float)IMG_S);
}
__device__ __forceinline__ float pix_y(int iy) {
    return -((2.0f * (float)iy + 1.0f - (float)IMG_S) * (1.0f / (float)IMG_S));
}

// ---- Pass 1: per-(view,chunk) z-buffer over 125 faces; packed (z,idx) out ----
__global__ __launch_bounds__(256) void raster_chunk_kernel(
    const float* __restrict__ verts,
    const int*   __restrict__ faces,
    unsigned long long* __restrict__ packed_out)
{
    __shared__ float4 fc[FPC][3];
    const int chunk = blockIdx.y;
    const int view  = blockIdx.z;
    const int fbase = chunk * FPC;

    if (threadIdx.x < FPC) {
        FaceCoef c = compute_face(verts, faces, fbase + (int)threadIdx.x, view);
        fc[threadIdx.x][0] = make_float4(c.A0, c.B0, c.C0, c.A1);
        fc[threadIdx.x][1] = make_float4(c.B1, c.C1, c.A2, c.B2);
        fc[threadIdx.x][2] = make_float4(c.C2, c.Az, c.Bz, c.Cz);
    }
    __syncthreads();

    const int pix = blockIdx.x * blockDim.x + threadIdx.x;
    const float px = pix_x(pix & (IMG_S - 1));
    const float py = pix_y(pix >> 8);

    float bestz = INFINITY;
    int besti = -1;

    for (int f = 0; f < FPC; ++f) {
        float4 q0 = fc[f][0];
        float4 q1 = fc[f][1];
        float4 q2 = fc[f][2];
        float w0 = fmaf(px, q0.x, fmaf(py, q0.y, q0.z));
        float w1 = fmaf(px, q0.w, fmaf(py, q1.x, q1.y));
        float w2 = fmaf(px, q1.z, fmaf(py, q1.w, q2.x));
        float z  = fmaf(px, q2.y, fmaf(py, q2.z, q2.w));
        float wmin = fminf(w0, fminf(w1, w2));
        float s = fminf(z, bestz - z);   // >0 iff z>0 && z<bestz (bestz>0 invariant)
        bool c = (wmin >= 0.0f) && (s > 0.0f);
        bestz = c ? z : bestz;           // strict < keeps first index on ties
        besti = c ? f : besti;
    }

    unsigned long long packed;
    if (besti >= 0)
        packed = ((unsigned long long)__float_as_uint(bestz) << 32) |
                 (unsigned int)(fbase + besti);
    else
        packed = ~0ull;
    packed_out[(size_t)(view * NCHUNK + chunk) * NPIX + pix] = packed;
}

// ---- Pass 2: merge chunks, shade winner, per-pixel loss, block partials ----
__global__ __launch_bounds__(256) void shade_loss_kernel(
    const float* __restrict__ verts,
    const int*   __restrict__ faces,
    const float* __restrict__ tex,
    const float* __restrict__ ref0,
    const float* __restrict__ ref1,
    const unsigned long long* __restrict__ packed_in,
    float* __restrict__ partials)
{
    __shared__ float red[4];
    const int gid  = blockIdx.x * blockDim.x + threadIdx.x;  // 0..131071
    const int view = gid >> 16;
    const int pix  = gid & (NPIX - 1);

    const unsigned long long* p = packed_in + (size_t)view * NCHUNK * NPIX + pix;
    unsigned long long best = p[0];
    #pragma unroll
    for (int c = 1; c < NCHUNK; ++c) {
        unsigned long long v = p[(size_t)c * NPIX];
        best = (v < best) ? v : best;   // packed min == argmin w/ first-idx ties
    }

    float c0 = 0.0f, c1 = 0.0f, c2 = 0.0f;
    if (best != ~0ull) {
        int fidx = (int)(best & 0xFFFFFFFFu);
        FaceCoef fcw = compute_face(verts, faces, fidx, view);
        const float px = pix_x(pix & (IMG_S - 1));
        const float py = pix_y(pix >> 8);
        float w0 = fmaf(px, fcw.A0, fmaf(py, fcw.B0, fcw.C0));
        float w1 = fmaf(px, fcw.A1, fmaf(py, fcw.B1, fcw.C1));
        float w2 = fmaf(px, fcw.A2, fmaf(py, fcw.B2, fcw.C2));
        int t0 = (int)fminf(fmaxf(rintf(w0 * (float)(TSZ - 1)), 0.0f), (float)(TSZ - 1));
        int t1 = (int)fminf(fmaxf(rintf(w1 * (float)(TSZ - 1)), 0.0f), (float)(TSZ - 1));
        int t2 = (int)fminf(fmaxf(rintf(w2 * (float)(TSZ - 1)), 0.0f), (float)(TSZ - 1));
        int flat = ((fidx * TSZ + t0) * TSZ + t1) * TSZ + t2;
        const float* t = tex + (long)flat * 3;
        c0 = tanhf(t[0]);
        c1 = tanhf(t[1]);
        c2 = tanhf(t[2]);
    }

    const float* __restrict__ ref = (view == 0) ? ref0 : ref1;
    float d0 = c0 - ref[0 * NPIX + pix];
    float d1 = c1 - ref[1 * NPIX + pix];
    float d2 = c2 - ref[2 * NPIX + pix];
    float acc = fmaf(d0, d0, fmaf(d1, d1, d2 * d2));

    for (int off = 32; off > 0; off >>= 1)
        acc += __shfl_down(acc, off, 64);
    int lane = threadIdx.x & 63;
    int wid = threadIdx.x >> 6;
    if (lane == 0) red[wid] = acc;
    __syncthreads();
    if (threadIdx.x == 0)
        partials[blockIdx.x] = red[0] + red[1] + red[2] + red[3];
}

__global__ __launch_bounds__(256) void reduce_kernel(const float* __restrict__ partials,
                                                     int n, float* __restrict__ out) {
    __shared__ float red[4];
    float v = 0.0f;
    for (int i = threadIdx.x; i < n; i += 256) v += partials[i];
    for (int off = 32; off > 0; off >>= 1)
        v += __shfl_down(v, off, 64);
    int lane = threadIdx.x & 63;
    int wid = threadIdx.x >> 6;
    if (lane == 0) red[wid] = v;
    __syncthreads();
    if (threadIdx.x == 0)
        out[0] = 0.5f * (red[0] + red[1] + red[2] + red[3]);
}

extern "C" void kernel_launch(void* const* d_in, const int* in_sizes, int n_in,
                              void* d_out, int out_size, void* d_ws, size_t ws_size,
                              hipStream_t stream) {
    const float* verts = (const float*)d_in[0];
    const int*   faces = (const int*)d_in[1];
    const float* tex   = (const float*)d_in[2];
    const float* ref0  = (const float*)d_in[3];
    const float* ref1  = (const float*)d_in[4];
    float* out = (float*)d_out;

    unsigned long long* packed = (unsigned long long*)d_ws;          // 2*4*65536*8 = 4 MB
    float* partials = (float*)((char*)d_ws + (size_t)2 * NCHUNK * NPIX * 8);  // 512 floats

    dim3 grid1(NPIX / 256, NCHUNK, 2);
    raster_chunk_kernel<<<grid1, 256, 0, stream>>>(verts, faces, packed);

    const int shade_blocks = (2 * NPIX) / 256;  // 512
    shade_loss_kernel<<<shade_blocks, 256, 0, stream>>>(verts, faces, tex, ref0, ref1,
                                                        packed, partials);
    reduce_kernel<<<1, 256, 0, stream>>>(partials, shade_blocks, out);
}

// Round 3
// 88.055 us; speedup vs baseline: 1.1075x; 1.0650x over previous
//
#include <hip/hip_runtime.h>
#include <math.h>

#define IMG_S 256
#define NPIX (IMG_S * IMG_S)
#define NFACE 500
#define NCHUNK 8
#define FPC_MAX 63           // ceil(500/8); last chunk has 59
#define PPT 8                // pixels (rows) per thread
#define TSZ 6
#define DIST 2.732f

// w_i = A_i*px + B_i*py + C_i  (edge fn pre-multiplied by 1/area)
// z   = Az*px + Bz*py + Cz
struct FaceCoef {
    float A0, B0, C0, A1, B1, C1, A2, B2, C2, Az, Bz, Cz;
};

__device__ __forceinline__ void edge_coef(float ax, float ay, float bx, float by,
                                          float inv, float& A, float& B, float& C) {
    float dy = by - ay;
    float dx = bx - ax;
    A = dy * inv;
    B = -dx * inv;
    C = (ay * dx - ax * dy) * inv;
}

__device__ __forceinline__ FaceCoef compute_face(const float* __restrict__ verts,
                                                 const int* __restrict__ faces,
                                                 int f, int view) {
    int i0 = faces[f * 3 + 0];
    int i1 = faces[f * 3 + 1];
    int i2 = faces[f * 3 + 2];

    float v0x = verts[i0 * 3 + 0], v0y = verts[i0 * 3 + 1], v0z = verts[i0 * 3 + 2];
    float v1x = verts[i1 * 3 + 0], v1y = verts[i1 * 3 + 1], v1z = verts[i1 * 3 + 2];
    float v2x = verts[i2 * 3 + 0], v2y = verts[i2 * 3 + 1], v2z = verts[i2 * 3 + 2];

    float p0x, p0y, p0z, p1x, p1y, p1z, p2x, p2y, p2z;
    if (view == 0) {
        // eye=(0,0,+D): v'=(-x, y, D-z)
        p0x = -v0x; p0y = v0y; p0z = DIST - v0z;
        p1x = -v1x; p1y = v1y; p1z = DIST - v1z;
        p2x = -v2x; p2y = v2y; p2z = DIST - v2z;
    } else {
        // eye=(0,0,-D): v'=(x, y, z+D)
        p0x = v0x; p0y = v0y; p0z = v0z + DIST;
        p1x = v1x; p1y = v1y; p1z = v1z + DIST;
        p2x = v2x; p2y = v2y; p2z = v2z + DIST;
    }

    float area = (p1x - p0x) * (p2y - p0y) - (p1y - p0y) * (p2x - p0x);
    bool ok = fabsf(area) > 1e-8f;

    FaceCoef fc;
    if (ok) {
        float inv = 1.0f / area;
        edge_coef(p1x, p1y, p2x, p2y, inv, fc.A0, fc.B0, fc.C0);  // e0 = edge(p1,p2)
        edge_coef(p2x, p2y, p0x, p0y, inv, fc.A1, fc.B1, fc.C1);  // e1 = edge(p2,p0)
        edge_coef(p0x, p0y, p1x, p1y, inv, fc.A2, fc.B2, fc.C2);  // e2 = edge(p0,p1)
        fc.Az = fc.A0 * p0z + fc.A1 * p1z + fc.A2 * p2z;
        fc.Bz = fc.B0 * p0z + fc.B1 * p1z + fc.B2 * p2z;
        fc.Cz = fc.C0 * p0z + fc.C1 * p1z + fc.C2 * p2z;
    } else {
        fc.A0 = fc.B0 = fc.A1 = fc.B1 = fc.A2 = fc.B2 = 0.0f;
        fc.C0 = fc.C1 = fc.C2 = -1.0f;   // inside-test always fails
        fc.Az = fc.Bz = fc.Cz = 0.0f;
    }
    return fc;
}

__device__ __forceinline__ float pix_x(int ix) {
    return (2.0f * (float)ix + 1.0f - (float)IMG_S) * (1.0f / (float)IMG_S);
}
__device__ __forceinline__ float pix_y(int iy) {
    return -((2.0f * (float)iy + 1.0f - (float)IMG_S) * (1.0f / (float)IMG_S));
}

// ---- Pass 1: per-(view,chunk) z-buffer; each thread owns 8 rows of one column ----
// LDS reads per face amortized over 8 pixels (LDS-issue was the R2 bottleneck).
__global__ __launch_bounds__(256) void raster_chunk_kernel(
    const float* __restrict__ verts,
    const int*   __restrict__ faces,
    unsigned long long* __restrict__ packed_out)
{
    __shared__ float4 fc[FPC_MAX][3];
    const int tile  = blockIdx.x;    // 0..31: rows [tile*8, tile*8+8)
    const int chunk = blockIdx.y;
    const int view  = blockIdx.z;
    const int fbase = chunk * FPC_MAX;
    const int flen  = min(FPC_MAX, NFACE - fbase);

    if ((int)threadIdx.x < flen) {
        FaceCoef c = compute_face(verts, faces, fbase + (int)threadIdx.x, view);
        fc[threadIdx.x][0] = make_float4(c.A0, c.B0, c.C0, c.A1);
        fc[threadIdx.x][1] = make_float4(c.B1, c.C1, c.A2, c.B2);
        fc[threadIdx.x][2] = make_float4(c.C2, c.Az, c.Bz, c.Cz);
    }
    __syncthreads();

    const int ix = threadIdx.x;          // column, per-lane
    const float px = pix_x(ix);
    float py[PPT];
    #pragma unroll
    for (int k = 0; k < PPT; ++k) py[k] = pix_y(tile * PPT + k);

    float bestz[PPT];
    int   besti[PPT];
    #pragma unroll
    for (int k = 0; k < PPT; ++k) { bestz[k] = INFINITY; besti[k] = -1; }

    for (int f = 0; f < flen; ++f) {
        float4 q0 = fc[f][0];
        float4 q1 = fc[f][1];
        float4 q2 = fc[f][2];
        // hoist the px-dependent part (per-lane, once per face)
        float d0 = fmaf(px, q0.x, q0.z);   // A0*px + C0
        float d1 = fmaf(px, q0.w, q1.y);   // A1*px + C1
        float d2 = fmaf(px, q1.z, q2.x);   // A2*px + C2
        float dz = fmaf(px, q2.y, q2.w);   // Az*px + Cz
        #pragma unroll
        for (int k = 0; k < PPT; ++k) {
            float w0 = fmaf(q0.y, py[k], d0);
            float w1 = fmaf(q1.x, py[k], d1);
            float w2 = fmaf(q1.w, py[k], d2);
            float z  = fmaf(q2.z, py[k], dz);
            float wmin = fminf(w0, fminf(w1, w2));
            float s = fminf(z, bestz[k] - z);   // >0 iff z>0 && z<bestz
            bool c = (wmin >= 0.0f) && (s > 0.0f);
            bestz[k] = c ? z : bestz[k];        // strict < keeps first index on ties
            besti[k] = c ? f : besti[k];
        }
    }

    unsigned long long* __restrict__ outp =
        packed_out + (size_t)(view * NCHUNK + chunk) * NPIX + tile * (PPT * IMG_S) + ix;
    #pragma unroll
    for (int k = 0; k < PPT; ++k) {
        unsigned long long packed;
        if (besti[k] >= 0)
            packed = ((unsigned long long)__float_as_uint(bestz[k]) << 32) |
                     (unsigned int)(fbase + besti[k]);
        else
            packed = ~0ull;
        outp[k * IMG_S] = packed;
    }
}

// ---- Pass 2: merge chunks, shade winner, per-pixel loss, block partials ----
__global__ __launch_bounds__(256) void shade_loss_kernel(
    const float* __restrict__ verts,
    const int*   __restrict__ faces,
    const float* __restrict__ tex,
    const float* __restrict__ ref0,
    const float* __restrict__ ref1,
    const unsigned long long* __restrict__ packed_in,
    float* __restrict__ partials)
{
    __shared__ float red[4];
    const int gid  = blockIdx.x * blockDim.x + threadIdx.x;  // 0..131071
    const int view = gid >> 16;
    const int pix  = gid & (NPIX - 1);

    const unsigned long long* p = packed_in + (size_t)view * NCHUNK * NPIX + pix;
    unsigned long long best = p[0];
    #pragma unroll
    for (int c = 1; c < NCHUNK; ++c) {
        unsigned long long v = p[(size_t)c * NPIX];
        best = (v < best) ? v : best;   // packed min == argmin w/ first-idx ties
    }

    float c0 = 0.0f, c1 = 0.0f, c2 = 0.0f;
    if (best != ~0ull) {
        int fidx = (int)(best & 0xFFFFFFFFu);
        FaceCoef fcw = compute_face(verts, faces, fidx, view);
        const float px = pix_x(pix & (IMG_S - 1));
        const float py = pix_y(pix >> 8);
        float w0 = fmaf(px, fcw.A0, fmaf(py, fcw.B0, fcw.C0));
        float w1 = fmaf(px, fcw.A1, fmaf(py, fcw.B1, fcw.C1));
        float w2 = fmaf(px, fcw.A2, fmaf(py, fcw.B2, fcw.C2));
        int t0 = (int)fminf(fmaxf(rintf(w0 * (float)(TSZ - 1)), 0.0f), (float)(TSZ - 1));
        int t1 = (int)fminf(fmaxf(rintf(w1 * (float)(TSZ - 1)), 0.0f), (float)(TSZ - 1));
        int t2 = (int)fminf(fmaxf(rintf(w2 * (float)(TSZ - 1)), 0.0f), (float)(TSZ - 1));
        int flat = ((fidx * TSZ + t0) * TSZ + t1) * TSZ + t2;
        const float* t = tex + (long)flat * 3;
        c0 = tanhf(t[0]);
        c1 = tanhf(t[1]);
        c2 = tanhf(t[2]);
    }

    const float* __restrict__ ref = (view == 0) ? ref0 : ref1;
    float d0 = c0 - ref[0 * NPIX + pix];
    float d1 = c1 - ref[1 * NPIX + pix];
    float d2 = c2 - ref[2 * NPIX + pix];
    float acc = fmaf(d0, d0, fmaf(d1, d1, d2 * d2));

    for (int off = 32; off > 0; off >>= 1)
        acc += __shfl_down(acc, off, 64);
    int lane = threadIdx.x & 63;
    int wid = threadIdx.x >> 6;
    if (lane == 0) red[wid] = acc;
    __syncthreads();
    if (threadIdx.x == 0)
        partials[blockIdx.x] = red[0] + red[1] + red[2] + red[3];
}

__global__ __launch_bounds__(256) void reduce_kernel(const float* __restrict__ partials,
                                                     int n, float* __restrict__ out) {
    __shared__ float red[4];
    float v = 0.0f;
    for (int i = threadIdx.x; i < n; i += 256) v += partials[i];
    for (int off = 32; off > 0; off >>= 1)
        v += __shfl_down(v, off, 64);
    int lane = threadIdx.x & 63;
    int wid = threadIdx.x >> 6;
    if (lane == 0) red[wid] = v;
    __syncthreads();
    if (threadIdx.x == 0)
        out[0] = 0.5f * (red[0] + red[1] + red[2] + red[3]);
}

extern "C" void kernel_launch(void* const* d_in, const int* in_sizes, int n_in,
                              void* d_out, int out_size, void* d_ws, size_t ws_size,
                              hipStream_t stream) {
    const float* verts = (const float*)d_in[0];
    const int*   faces = (const int*)d_in[1];
    const float* tex   = (const float*)d_in[2];
    const float* ref0  = (const float*)d_in[3];
    const float* ref1  = (const float*)d_in[4];
    float* out = (float*)d_out;

    unsigned long long* packed = (unsigned long long*)d_ws;  // 2*8*65536*8 = 8 MB
    float* partials = (float*)((char*)d_ws + (size_t)2 * NCHUNK * NPIX * 8);

    dim3 grid1(NPIX / (256 * PPT), NCHUNK, 2);   // (32, 8, 2) = 512 blocks
    raster_chunk_kernel<<<grid1, 256, 0, stream>>>(verts, faces, packed);

    const int shade_blocks = (2 * NPIX) / 256;   // 512
    shade_loss_kernel<<<shade_blocks, 256, 0, stream>>>(verts, faces, tex, ref0, ref1,
                                                        packed, partials);
    reduce_kernel<<<1, 256, 0, stream>>>(partials, shade_blocks, out);
}